// Round 3
// baseline (714.368 us; speedup 1.0000x reference)
//
#include <hip/hip_runtime.h>
#include <stdint.h>

#define TK_F       4096
#define TK_RPB     4            // rows (waves) per block
#define TK_THREADS (TK_RPB * 64)

// order-preserving float<->uint transforms: larger float <=> larger uint
__device__ __forceinline__ unsigned tk_f2u(unsigned b) {
    return b ^ ((unsigned)(((int)b) >> 31) | 0x80000000u);
}
__device__ __forceinline__ unsigned tk_u2f(unsigned u) {
    return u ^ ((~(unsigned)(((int)u) >> 31)) | 0x80000000u);
}

// drain all outstanding LDS ops of this wave; memory clobber stops compiler motion
__device__ __forceinline__ void tk_lds_fence() {
    __asm__ volatile("s_waitcnt lgkmcnt(0)" ::: "memory");
}

// rare tie-straddle path: # of elements equal to T before column idx
__device__ __attribute__((noinline))
unsigned tk_count_eq_before(const unsigned* __restrict__ xr, int idx, unsigned T) {
    unsigned c = 0;
    for (int i = 0; i < idx; ++i) c += (tk_f2u(xr[i]) == T) ? 1u : 0u;
    return c;
}

__global__ __launch_bounds__(TK_THREADS, 4)
void tk_topk_mask(const float* __restrict__ x, const int* __restrict__ kp,
                  float* __restrict__ out, int B)
{
    __shared__ unsigned hist[TK_RPB][2048];   // per-wave private histogram

    const int lane = threadIdx.x & 63;
    const int wid  = threadIdx.x >> 6;
    const int row  = blockIdx.x * TK_RPB + wid;
    if (row >= B) return;                     // wave-uniform

    const unsigned k = (unsigned)kp[0];

    const uint4* xv = (const uint4*)(x + (size_t)row * TK_F);
    uint4*       ov = (uint4*)(out + (size_t)row * TK_F);

    // ---- load row: 16 x uint4 per lane, keep as orderable uints in VGPRs ----
    unsigned u[64];
    #pragma unroll
    for (int v = 0; v < 16; ++v) {
        uint4 q = xv[lane + 64 * v];
        u[4*v+0] = tk_f2u(q.x); u[4*v+1] = tk_f2u(q.y);
        u[4*v+2] = tk_f2u(q.z); u[4*v+3] = tk_f2u(q.w);
    }

    if (k == 0) {
        uint4 z = make_uint4(0u, 0u, 0u, 0u);
        #pragma unroll
        for (int v = 0; v < 16; ++v) ov[lane + 64 * v] = z;
        return;
    }
    if (k >= TK_F) {
        #pragma unroll
        for (int v = 0; v < 16; ++v) {
            uint4 q;
            q.x = tk_u2f(u[4*v+0]); q.y = tk_u2f(u[4*v+1]);
            q.z = tk_u2f(u[4*v+2]); q.w = tk_u2f(u[4*v+3]);
            ov[lane + 64 * v] = q;
        }
        return;
    }

    unsigned* h = &hist[wid][0];
    unsigned r = k;                            // rank (1-based) within current group
    unsigned prefix = 0;                       // value bits fixed so far
    unsigned eTot = 0;                         // equals-count at final level

    // ================= level 0: bits [31:21], 2048 bins =================
    {
        uint4 z4 = make_uint4(0u, 0u, 0u, 0u);
        #pragma unroll
        for (int i = 0; i < 8; ++i) ((uint4*)h)[lane + 64 * i] = z4;
        tk_lds_fence();                        // clears visible before atomics

        #pragma unroll
        for (int e = 0; e < 64; ++e) atomicAdd(&h[u[e] >> 21], 1u);
        tk_lds_fence();                        // atomics visible before reads

        // my 32-bin total (bins [lane*32, lane*32+32))
        unsigned s = 0;
        {
            const uint4* hb = (const uint4*)&h[lane * 32];
            #pragma unroll
            for (int i = 0; i < 8; ++i) { uint4 q = hb[i]; s += q.x + q.y + q.z + q.w; }
        }
        // wave inclusive suffix-sum (higher lanes = higher bins = larger values)
        unsigned acc = s;
        #pragma unroll
        for (int d = 1; d < 64; d <<= 1) {
            unsigned v = (unsigned)__shfl_down((int)acc, d, 64);
            if (lane + d < 64) acc += v;
        }
        unsigned run = acc - s;                // count in bins above my range
        int fbin = -1; unsigned frun = 0;
        #pragma unroll
        for (int j = 31; j >= 0; --j) {        // descending within my range
            unsigned hh = h[lane * 32 + j];
            if (fbin < 0 && run < r && run + hh >= r) { fbin = lane * 32 + j; frun = run; }
            run += hh;
        }
        // register broadcast of the unique finder (no LDS ordering involved)
        unsigned long long m = __ballot(fbin >= 0);
        int src = __ffsll((unsigned long long)m) - 1;
        prefix = (unsigned)__shfl(fbin, src, 64);
        r     -= (unsigned)__shfl((int)frun, src, 64);
    }

    // ============ levels 1..3: 7-bit digits, 128 bins each ============
    #pragma unroll
    for (int l = 0; l < 3; ++l) {
        const int sm = 21 - 7 * l;             // (u >> sm) == prefix selects group
        const int sd = sm - 7;                 // digit bits [sm-1 : sd]

        h[lane] = 0u; h[lane + 64] = 0u;       // clear 128 bins
        tk_lds_fence();

        #pragma unroll
        for (int e = 0; e < 64; ++e) {
            if ((u[e] >> sm) == prefix)
                atomicAdd(&h[(u[e] >> sd) & 127u], 1u);
        }
        tk_lds_fence();

        unsigned h0 = h[lane * 2], h1 = h[lane * 2 + 1];
        unsigned ss = h0 + h1;
        unsigned ac = ss;
        #pragma unroll
        for (int d = 1; d < 64; d <<= 1) {
            unsigned v = (unsigned)__shfl_down((int)ac, d, 64);
            if (lane + d < 64) ac += v;
        }
        unsigned rn = ac - ss;                 // count in digits above my pair
        int fd = -1; unsigned fr = 0, fe = 0;
        if (rn < r && rn + h1 >= r) { fd = lane * 2 + 1; fr = rn; fe = h1; }
        rn += h1;
        if (fd < 0 && rn < r && rn + h0 >= r) { fd = lane * 2; fr = rn; fe = h0; }

        unsigned long long m = __ballot(fd >= 0);
        int src = __ffsll((unsigned long long)m) - 1;
        unsigned dg = (unsigned)__shfl(fd, src, 64);
        r    -= (unsigned)__shfl((int)fr, src, 64);
        eTot  = (unsigned)__shfl((int)fe, src, 64);
        prefix = (prefix << 7) | dg;
    }

    // ---- epilogue: T = k-th largest value (uint domain), exact tie handling ----
    const unsigned T  = prefix;
    const unsigned re = r;                     // # of equals-to-T to include
    const bool easy = (eTot == re);            // no tie straddling the cut (common)
    const unsigned* xr = (const unsigned*)(x + (size_t)row * TK_F);

    #pragma unroll
    for (int v = 0; v < 16; ++v) {
        uint4 q;
        #pragma unroll
        for (int c = 0; c < 4; ++c) {
            unsigned uu  = u[4*v + c];
            unsigned val = 0u;
            if (uu > T) {
                val = tk_u2f(uu);
            } else if (uu == T) {
                if (easy) {
                    val = tk_u2f(uu);
                } else {
                    int idx = 4 * (lane + 64 * v) + c;
                    if (tk_count_eq_before(xr, idx, T) < re) val = tk_u2f(uu);
                }
            }
            (&q.x)[c] = val;
        }
        ov[lane + 64 * v] = q;
    }
}

extern "C" void kernel_launch(void* const* d_in, const int* in_sizes, int n_in,
                              void* d_out, int out_size, void* d_ws, size_t ws_size,
                              hipStream_t stream) {
    const float* x   = (const float*)d_in[0];
    const int*   kpp = (const int*)d_in[1];
    float*       o   = (float*)d_out;
    const int B = in_sizes[0] / TK_F;
    const int grid = (B + TK_RPB - 1) / TK_RPB;
    hipLaunchKernelGGL(tk_topk_mask, dim3(grid), dim3(TK_THREADS), 0, stream,
                       x, kpp, o, B);
}

// Round 4
// 671.336 us; speedup vs baseline: 1.0641x; 1.0641x over previous
//
#include <hip/hip_runtime.h>
#include <stdint.h>

#define TK_F       4096
#define TK_RPB     4                      // rows (waves) per block
#define TK_THREADS (TK_RPB * 64)
#define TK_NBIN    1024                   // 10-bit level-0 histogram
#define TK_HPAD    (TK_NBIN + TK_NBIN/16) // +1 word per 16 bins: bank-conflict-free scan
#define TK_CAP     256                    // candidate list capacity

// order-preserving float<->uint transforms: larger float <=> larger uint
__device__ __forceinline__ unsigned tk_f2u(unsigned b) {
    return b ^ ((unsigned)(((int)b) >> 31) | 0x80000000u);
}
__device__ __forceinline__ unsigned tk_u2f(unsigned u) {
    return u ^ ((~(unsigned)(((int)u) >> 31)) | 0x80000000u);
}
__device__ __forceinline__ int tk_pad(int i) { return i + (i >> 4); }
// drain this wave's LDS ops; memory clobber also stops cross-pass load CSE
__device__ __forceinline__ void tk_fence() {
    __asm__ volatile("s_waitcnt lgkmcnt(0)" ::: "memory");
}

// rare tie-straddle path: # of elements equal to T before column idx
__device__ __attribute__((noinline))
unsigned tk_count_eq_before(const unsigned* __restrict__ xr, int idx, unsigned T) {
    unsigned c = 0;
    for (int i = 0; i < idx; ++i) c += (tk_f2u(xr[i]) == T) ? 1u : 0u;
    return c;
}

__global__ __launch_bounds__(TK_THREADS)
void tk_topk_mask(const float* __restrict__ x, const int* __restrict__ kp,
                  float* __restrict__ out, int B)
{
    __shared__ unsigned hist[TK_RPB][TK_HPAD];
    __shared__ unsigned cand[TK_RPB][TK_CAP];
    __shared__ unsigned ccnt[TK_RPB];

    const int lane = threadIdx.x & 63;
    const int wid  = threadIdx.x >> 6;
    const int row  = blockIdx.x * TK_RPB + wid;
    if (row >= B) return;                      // wave-uniform

    const unsigned k = (unsigned)kp[0];
    const uint4* xv = (const uint4*)(x + (size_t)row * TK_F);
    uint4*       ov = (uint4*)(out + (size_t)row * TK_F);

    if (k == 0) {
        uint4 z = make_uint4(0u, 0u, 0u, 0u);
        #pragma unroll
        for (int v = 0; v < 16; ++v) ov[lane + 64 * v] = z;
        return;
    }
    if (k >= TK_F) {
        #pragma unroll
        for (int v = 0; v < 16; ++v) ov[lane + 64 * v] = xv[lane + 64 * v];
        return;
    }

    unsigned* h = hist[wid];
    for (int i = lane; i < TK_HPAD; i += 64) h[i] = 0u;
    if (lane == 0) ccnt[wid] = 0u;
    tk_fence();                                 // clears visible before atomics

    // ---------------- pass 1: 1024-bin histogram (streams row from HBM) ----
    #pragma unroll
    for (int v = 0; v < 16; ++v) {
        uint4 q = xv[lane + 64 * v];
        atomicAdd(&h[tk_pad(tk_f2u(q.x) >> 22)], 1u);
        atomicAdd(&h[tk_pad(tk_f2u(q.y) >> 22)], 1u);
        atomicAdd(&h[tk_pad(tk_f2u(q.z) >> 22)], 1u);
        atomicAdd(&h[tk_pad(tk_f2u(q.w) >> 22)], 1u);
    }
    tk_fence();                                 // atomics visible before reads

    // ---------------- suffix scan: lane owns bins [16*lane, 16*lane+16) ----
    unsigned hb[16], s = 0;
    const int base = lane * 16;
    #pragma unroll
    for (int j = 0; j < 16; ++j) { hb[j] = h[tk_pad(base + j)]; s += hb[j]; }
    unsigned acc = s;                           // wave inclusive suffix-sum
    #pragma unroll
    for (int d = 1; d < 64; d <<= 1) {
        unsigned t = (unsigned)__shfl_down((int)acc, d, 64);
        if (lane + d < 64) acc += t;
    }
    unsigned run = acc - s;                     // count in bins above my range
    int fbin = -1; unsigned frun = 0;
    #pragma unroll
    for (int j = 15; j >= 0; --j) {             // descending within my range
        unsigned hh = hb[j];
        if (fbin < 0 && run < k && run + hh >= k) { fbin = base + j; frun = run; }
        run += hh;
    }
    unsigned long long m0 = __ballot(fbin >= 0);
    int src0 = __ffsll(m0) - 1;
    const unsigned prefix = (unsigned)__shfl(fbin, src0, 64);
    unsigned r = k - (unsigned)__shfl((int)frun, src0, 64);  // rank inside bin

    // ---------------- pass 2: collect threshold-bin candidates (cache-hot) --
    unsigned* cd = cand[wid];
    #pragma unroll
    for (int v = 0; v < 16; ++v) {
        uint4 q = xv[lane + 64 * v];
        #pragma unroll
        for (int c = 0; c < 4; ++c) {
            unsigned uu = tk_f2u((&q.x)[c]);
            if ((uu >> 22) == prefix) {
                unsigned p = atomicAdd(&ccnt[wid], 1u);
                if (p < TK_CAP) cd[p] = uu;
            }
        }
    }
    tk_fence();
    const unsigned L = ccnt[wid];

    unsigned T, re; bool easy;
    if (L <= TK_CAP) {
        // exact rank within candidate list (reads are all-lane broadcasts)
        int fnd = 0; unsigned mT = 0, mg = 0, me = 0;
        for (unsigned j = lane; j < L; j += 64) {
            unsigned uj = cd[j], g = 0, eq = 0;
            for (unsigned i = 0; i < L; ++i) {
                unsigned ui = cd[i];
                g  += (ui > uj)  ? 1u : 0u;
                eq += (ui == uj) ? 1u : 0u;
            }
            if (g < r && g + eq >= r) { fnd = 1; mT = uj; mg = g; me = eq; }
        }
        unsigned long long mm = __ballot(fnd);
        int s2 = __ffsll(mm) - 1;
        T           = (unsigned)__shfl((int)mT, s2, 64);
        unsigned g  = (unsigned)__shfl((int)mg, s2, 64);
        unsigned e  = (unsigned)__shfl((int)me, s2, 64);
        re = r - g; easy = (e == re);
    } else {
        // overflow fallback (never expected): bitwise radix refinement
        unsigned pfx = prefix, rr = r;
        for (int sh = 21; sh >= 0; --sh) {
            unsigned cp = (pfx << 1) | 1u;
            unsigned c = 0;
            for (int v = 0; v < 16; ++v) {
                uint4 q = xv[lane + 64 * v];
                c += ((tk_f2u(q.x) >> sh) == cp) ? 1u : 0u;
                c += ((tk_f2u(q.y) >> sh) == cp) ? 1u : 0u;
                c += ((tk_f2u(q.z) >> sh) == cp) ? 1u : 0u;
                c += ((tk_f2u(q.w) >> sh) == cp) ? 1u : 0u;
            }
            #pragma unroll
            for (int d = 1; d < 64; d <<= 1) c += (unsigned)__shfl_xor((int)c, d, 64);
            if (c >= rr) pfx = cp; else { rr -= c; pfx <<= 1; }
        }
        T = pfx;
        unsigned ce = 0;
        for (int v = 0; v < 16; ++v) {
            uint4 q = xv[lane + 64 * v];
            ce += (tk_f2u(q.x) == T) ? 1u : 0u;
            ce += (tk_f2u(q.y) == T) ? 1u : 0u;
            ce += (tk_f2u(q.z) == T) ? 1u : 0u;
            ce += (tk_f2u(q.w) == T) ? 1u : 0u;
        }
        #pragma unroll
        for (int d = 1; d < 64; d <<= 1) ce += (unsigned)__shfl_xor((int)ce, d, 64);
        re = rr; easy = (ce == rr);
    }

    // ---------------- pass 3: apply mask, stream out (cache-hot reload) ----
    const unsigned* xr = (const unsigned*)(x + (size_t)row * TK_F);
    #pragma unroll
    for (int v = 0; v < 16; ++v) {
        uint4 q = xv[lane + 64 * v];
        uint4 o4;
        #pragma unroll
        for (int c = 0; c < 4; ++c) {
            unsigned uu  = tk_f2u((&q.x)[c]);
            unsigned val = 0u;
            if (uu > T) {
                val = tk_u2f(uu);
            } else if (uu == T) {
                if (easy) {
                    val = tk_u2f(uu);
                } else {
                    int idx = 4 * (lane + 64 * v) + c;
                    if (tk_count_eq_before(xr, idx, T) < re) val = tk_u2f(uu);
                }
            }
            (&o4.x)[c] = val;
        }
        ov[lane + 64 * v] = o4;
    }
}

extern "C" void kernel_launch(void* const* d_in, const int* in_sizes, int n_in,
                              void* d_out, int out_size, void* d_ws, size_t ws_size,
                              hipStream_t stream) {
    const float* x   = (const float*)d_in[0];
    const int*   kpp = (const int*)d_in[1];
    float*       o   = (float*)d_out;
    const int B = in_sizes[0] / TK_F;
    const int grid = (B + TK_RPB - 1) / TK_RPB;
    hipLaunchKernelGGL(tk_topk_mask, dim3(grid), dim3(TK_THREADS), 0, stream,
                       x, kpp, o, B);
}

// Round 5
// 626.701 us; speedup vs baseline: 1.1399x; 1.0712x over previous
//
#include <hip/hip_runtime.h>
#include <stdint.h>

#define TK_F   4096
#define TK_CAP 128

// order-preserving float<->uint transforms: larger float <=> larger uint
__device__ __forceinline__ unsigned tk_f2u(unsigned b) {
    return b ^ ((unsigned)(((int)b) >> 31) | 0x80000000u);
}
__device__ __forceinline__ unsigned tk_u2f(unsigned u) {
    return u ^ ((~(unsigned)(((int)u) >> 31)) | 0x80000000u);
}

// rare tie-straddle path: # of elements equal to T before column idx
__device__ __attribute__((noinline))
unsigned tk_count_eq_before(const unsigned* __restrict__ xr, int idx, unsigned T) {
    unsigned c = 0;
    for (int i = 0; i < idx; ++i) c += (tk_f2u(xr[i]) == T) ? 1u : 0u;
    return c;
}

__global__ __launch_bounds__(64)
void tk_topk_mask(const float* __restrict__ x, const int* __restrict__ kp,
                  float* __restrict__ out, int B)
{
    __shared__ unsigned h[2048];     // radix histogram (one wave owns the block)
    __shared__ unsigned cand[TK_CAP];
    __shared__ unsigned cnt;

    const int lane = threadIdx.x;    // 0..63
    const int row  = blockIdx.x;
    const unsigned k = (unsigned)kp[0];

    const uint4* xv = (const uint4*)(x + (size_t)row * TK_F);
    uint4*       ov = (uint4*)(out + (size_t)row * TK_F);

    // ---- single global read: row lives in 64 VGPRs/lane as orderable uints ----
    uint4 u4[16];
    #pragma unroll
    for (int v = 0; v < 16; ++v) {
        uint4 q = xv[lane + 64 * v];
        q.x = tk_f2u(q.x); q.y = tk_f2u(q.y);
        q.z = tk_f2u(q.z); q.w = tk_f2u(q.w);
        u4[v] = q;
    }

    if (k == 0) {
        uint4 z = make_uint4(0u, 0u, 0u, 0u);
        #pragma unroll
        for (int v = 0; v < 16; ++v) ov[lane + 64 * v] = z;
        return;
    }
    if (k >= TK_F) {
        #pragma unroll
        for (int v = 0; v < 16; ++v) {
            uint4 q = u4[v];
            q.x = tk_u2f(q.x); q.y = tk_u2f(q.y);
            q.z = tk_u2f(q.z); q.w = tk_u2f(q.w);
            ov[lane + 64 * v] = q;
        }
        return;
    }

    const uint4 z4 = make_uint4(0u, 0u, 0u, 0u);

    // ================= level 0: bits [31:21], 2048 bins =================
    #pragma unroll
    for (int i = 0; i < 8; ++i) ((uint4*)h)[lane + 64 * i] = z4;
    if (lane == 0) cnt = 0u;
    __syncthreads();

    #pragma unroll
    for (int v = 0; v < 16; ++v) {
        atomicAdd(&h[u4[v].x >> 21], 1u);
        atomicAdd(&h[u4[v].y >> 21], 1u);
        atomicAdd(&h[u4[v].z >> 21], 1u);
        atomicAdd(&h[u4[v].w >> 21], 1u);
    }
    __syncthreads();

    unsigned b0, r;
    {
        // my 32-bin total (bins [32*lane, 32*lane+32)), sum only (no reg cache)
        unsigned s = 0;
        {
            const uint4* hb = (const uint4*)&h[lane * 32];
            #pragma unroll
            for (int i = 0; i < 8; ++i) { uint4 q = hb[i]; s += q.x + q.y + q.z + q.w; }
        }
        unsigned acc = s;            // wave inclusive suffix-sum (high lanes = high bins)
        #pragma unroll
        for (int d = 1; d < 64; d <<= 1) {
            unsigned t = (unsigned)__shfl_down((int)acc, d, 64);
            if (lane + d < 64) acc += t;
        }
        unsigned run = acc - s;      // count in bins strictly above my range
        int fbin = -1; unsigned frun = 0;
        for (int j = 31; j >= 0; --j) {
            unsigned hh = h[lane * 32 + j];
            if (fbin < 0 && run < k && run + hh >= k) { fbin = lane * 32 + j; frun = run; }
            run += hh;
        }
        unsigned long long m = __ballot(fbin >= 0);
        int src = __ffsll(m) - 1;
        b0 = (unsigned)__shfl(fbin, src, 64);
        r  = k - (unsigned)__shfl((int)frun, src, 64);   // rank inside bin b0
    }
    __syncthreads();

    // ================= level 1: bits [20:10], 2048 bins =================
    #pragma unroll
    for (int i = 0; i < 8; ++i) ((uint4*)h)[lane + 64 * i] = z4;
    __syncthreads();

    #pragma unroll
    for (int v = 0; v < 16; ++v) {
        uint4 q = u4[v];
        if ((q.x >> 21) == b0) atomicAdd(&h[(q.x >> 10) & 2047u], 1u);
        if ((q.y >> 21) == b0) atomicAdd(&h[(q.y >> 10) & 2047u], 1u);
        if ((q.z >> 21) == b0) atomicAdd(&h[(q.z >> 10) & 2047u], 1u);
        if ((q.w >> 21) == b0) atomicAdd(&h[(q.w >> 10) & 2047u], 1u);
    }
    __syncthreads();

    unsigned b1, L;
    {
        unsigned s = 0;
        {
            const uint4* hb = (const uint4*)&h[lane * 32];
            #pragma unroll
            for (int i = 0; i < 8; ++i) { uint4 q = hb[i]; s += q.x + q.y + q.z + q.w; }
        }
        unsigned acc = s;
        #pragma unroll
        for (int d = 1; d < 64; d <<= 1) {
            unsigned t = (unsigned)__shfl_down((int)acc, d, 64);
            if (lane + d < 64) acc += t;
        }
        unsigned run = acc - s;
        int fbin = -1; unsigned frun = 0, fh = 0;
        for (int j = 31; j >= 0; --j) {
            unsigned hh = h[lane * 32 + j];
            if (fbin < 0 && run < r && run + hh >= r) { fbin = lane * 32 + j; frun = run; fh = hh; }
            run += hh;
        }
        unsigned long long m = __ballot(fbin >= 0);
        int src = __ffsll(m) - 1;
        b1 = (unsigned)__shfl(fbin, src, 64);
        r -= (unsigned)__shfl((int)frun, src, 64);       // rank inside 22-bit bin
        L  = (unsigned)__shfl((int)fh, src, 64);         // candidate count
    }

    const unsigned pfx22 = (b0 << 11) | b1;

    // ============ exact rank among the (typically 1-4) candidates ============
    unsigned T, re; bool easy;
    if (L <= TK_CAP) {
        #pragma unroll
        for (int v = 0; v < 16; ++v) {
            uint4 q = u4[v];
            if ((q.x >> 10) == pfx22) { unsigned p = atomicAdd(&cnt, 1u); cand[p] = q.x; }
            if ((q.y >> 10) == pfx22) { unsigned p = atomicAdd(&cnt, 1u); cand[p] = q.y; }
            if ((q.z >> 10) == pfx22) { unsigned p = atomicAdd(&cnt, 1u); cand[p] = q.z; }
            if ((q.w >> 10) == pfx22) { unsigned p = atomicAdd(&cnt, 1u); cand[p] = q.w; }
        }
        __syncthreads();
        int fnd = 0; unsigned mT = 0, mg = 0, me = 0;
        for (unsigned j = lane; j < L; j += 64) {
            unsigned uj = cand[j], g = 0, eq = 0;
            for (unsigned i = 0; i < L; ++i) {
                unsigned ui = cand[i];
                g  += (ui > uj)  ? 1u : 0u;
                eq += (ui == uj) ? 1u : 0u;
            }
            if (g < r && g + eq >= r) { fnd = 1; mT = uj; mg = g; me = eq; }
        }
        unsigned long long mm = __ballot(fnd);
        int s2 = __ffsll(mm) - 1;
        T          = (unsigned)__shfl((int)mT, s2, 64);
        unsigned g = (unsigned)__shfl((int)mg, s2, 64);
        unsigned e = (unsigned)__shfl((int)me, s2, 64);
        re = r - g; easy = (e == re);
    } else {
        // pathological (>128 elems share 22-bit prefix): bit-by-bit ballot refine
        unsigned pfx = pfx22, rr = r;
        for (int sh = 9; sh >= 0; --sh) {
            unsigned cp = (pfx << 1) | 1u;
            unsigned c = 0;
            #pragma unroll
            for (int v = 0; v < 16; ++v) {
                uint4 q = u4[v];
                c += ((q.x >> sh) == cp) ? 1u : 0u;
                c += ((q.y >> sh) == cp) ? 1u : 0u;
                c += ((q.z >> sh) == cp) ? 1u : 0u;
                c += ((q.w >> sh) == cp) ? 1u : 0u;
            }
            #pragma unroll
            for (int d = 1; d < 64; d <<= 1) c += (unsigned)__shfl_xor((int)c, d, 64);
            if (c >= rr) pfx = cp; else { rr -= c; pfx = pfx << 1; }
        }
        T = pfx;
        unsigned ce = 0;
        #pragma unroll
        for (int v = 0; v < 16; ++v) {
            uint4 q = u4[v];
            ce += (q.x == T) ? 1u : 0u;
            ce += (q.y == T) ? 1u : 0u;
            ce += (q.z == T) ? 1u : 0u;
            ce += (q.w == T) ? 1u : 0u;
        }
        #pragma unroll
        for (int d = 1; d < 64; d <<= 1) ce += (unsigned)__shfl_xor((int)ce, d, 64);
        re = rr; easy = (ce == rr);
    }

    // ---------------- mask + single global write (from registers) ----------
    const unsigned* xr = (const unsigned*)(x + (size_t)row * TK_F);
    #pragma unroll
    for (int v = 0; v < 16; ++v) {
        uint4 q = u4[v];
        uint4 o4;
        #pragma unroll
        for (int c = 0; c < 4; ++c) {
            unsigned uu  = (&q.x)[c];
            unsigned val = 0u;
            if (uu > T) {
                val = tk_u2f(uu);
            } else if (uu == T) {
                if (easy) {
                    val = tk_u2f(uu);
                } else {
                    int idx = 4 * (lane + 64 * v) + c;
                    if (tk_count_eq_before(xr, idx, T) < re) val = tk_u2f(uu);
                }
            }
            (&o4.x)[c] = val;
        }
        ov[lane + 64 * v] = o4;
    }
}

extern "C" void kernel_launch(void* const* d_in, const int* in_sizes, int n_in,
                              void* d_out, int out_size, void* d_ws, size_t ws_size,
                              hipStream_t stream) {
    const float* x   = (const float*)d_in[0];
    const int*   kpp = (const int*)d_in[1];
    float*       o   = (float*)d_out;
    const int B = in_sizes[0] / TK_F;
    hipLaunchKernelGGL(tk_topk_mask, dim3(B), dim3(64), 0, stream, x, kpp, o, B);
}

// Round 6
// 598.674 us; speedup vs baseline: 1.1933x; 1.0468x over previous
//
#include <hip/hip_runtime.h>
#include <stdint.h>

#define TK_F       4096
#define TK_WPB     16                 // waves (rows) per workgroup
#define TK_THREADS (TK_WPB * 64)      // 1024
#define TK_NB      1024               // level-0 bins: bits [31:22]
#define TK_CAP     256                // candidate capacity (aliases histogram)

// order-preserving float<->uint transforms: larger float <=> larger uint
__device__ __forceinline__ unsigned tk_f2u(unsigned b) {
    return b ^ ((unsigned)(((int)b) >> 31) | 0x80000000u);
}
__device__ __forceinline__ unsigned tk_u2f(unsigned u) {
    return u ^ ((~(unsigned)(((int)u) >> 31)) | 0x80000000u);
}
// drain this wave's LDS ops; clobber stops compiler reordering across phases
__device__ __forceinline__ void tk_fence() {
    __asm__ volatile("s_waitcnt lgkmcnt(0)" ::: "memory");
}

// rare tie-straddle path: # of elements equal to T before column idx
__device__ __attribute__((noinline))
unsigned tk_count_eq_before(const unsigned* __restrict__ xr, int idx, unsigned T) {
    unsigned c = 0;
    for (int i = 0; i < idx; ++i) c += (tk_f2u(xr[i]) == T) ? 1u : 0u;
    return c;
}

__global__ __launch_bounds__(TK_THREADS)
void tk_topk_mask(const float* __restrict__ x, const int* __restrict__ kp,
                  float* __restrict__ out, int B)
{
    __shared__ unsigned hist[TK_WPB][TK_NB];   // 64 KB, per-wave private
    __shared__ unsigned ccnt[TK_WPB];

    const int lane = threadIdx.x & 63;
    const int wid  = threadIdx.x >> 6;
    const int row  = blockIdx.x * TK_WPB + wid;
    if (row >= B) return;                      // wave-uniform; no barriers anywhere

    const unsigned k = (unsigned)kp[0];
    const uint4* xv = (const uint4*)(x + (size_t)row * TK_F);
    uint4*       ov = (uint4*)(out + (size_t)row * TK_F);

    // ---- single global read: row lives in 64 VGPRs/lane as orderable uints ----
    uint4 u4[16];
    #pragma unroll
    for (int v = 0; v < 16; ++v) {
        uint4 q = xv[lane + 64 * v];
        q.x = tk_f2u(q.x); q.y = tk_f2u(q.y);
        q.z = tk_f2u(q.z); q.w = tk_f2u(q.w);
        u4[v] = q;
    }

    if (k == 0) {
        uint4 z = make_uint4(0u, 0u, 0u, 0u);
        #pragma unroll
        for (int v = 0; v < 16; ++v) ov[lane + 64 * v] = z;
        return;
    }
    if (k >= TK_F) {
        #pragma unroll
        for (int v = 0; v < 16; ++v) {
            uint4 q = u4[v];
            q.x = tk_u2f(q.x); q.y = tk_u2f(q.y);
            q.z = tk_u2f(q.z); q.w = tk_u2f(q.w);
            ov[lane + 64 * v] = q;
        }
        return;
    }

    unsigned* h = &hist[wid][0];

    // ---- clear private histogram (4 x uint4 per lane) + counter ----
    {
        const uint4 z4 = make_uint4(0u, 0u, 0u, 0u);
        #pragma unroll
        for (int i = 0; i < 4; ++i) ((uint4*)h)[lane + 64 * i] = z4;
        if (lane == 0) ccnt[wid] = 0u;
    }
    tk_fence();

    // ---- level 0: 1024-bin histogram over bits [31:22] ----
    #pragma unroll
    for (int v = 0; v < 16; ++v) {
        atomicAdd(&h[u4[v].x >> 22], 1u);
        atomicAdd(&h[u4[v].y >> 22], 1u);
        atomicAdd(&h[u4[v].z >> 22], 1u);
        atomicAdd(&h[u4[v].w >> 22], 1u);
    }
    tk_fence();

    // ---- suffix scan: lane owns bins [16*lane, 16*lane+16) ----
    unsigned prefix, r, L;
    {
        unsigned s = 0;
        {
            const uint4* hb = (const uint4*)&h[lane * 16];
            #pragma unroll
            for (int i = 0; i < 4; ++i) { uint4 q = hb[i]; s += q.x + q.y + q.z + q.w; }
        }
        unsigned acc = s;                      // inclusive suffix-sum across lanes
        #pragma unroll
        for (int d = 1; d < 64; d <<= 1) {
            unsigned t = (unsigned)__shfl_down((int)acc, d, 64);
            if (lane + d < 64) acc += t;
        }
        unsigned run = acc - s;                // count in bins strictly above mine
        int fbin = -1; unsigned frun = 0, fh = 0;
        for (int j = 15; j >= 0; --j) {        // descending bins within my range
            unsigned hh = h[lane * 16 + j];
            if (fbin < 0 && run < k && run + hh >= k) { fbin = lane * 16 + j; frun = run; fh = hh; }
            run += hh;
        }
        unsigned long long m = __ballot(fbin >= 0);
        int src = __ffsll(m) - 1;
        prefix = (unsigned)__shfl(fbin, src, 64);
        r      = k - (unsigned)__shfl((int)frun, src, 64);  // rank inside bin
        L      = (unsigned)__shfl((int)fh, src, 64);        // bin population
    }
    tk_fence();                                 // hist dead; reuse as candidate list

    unsigned T, re; bool easy;
    if (L <= TK_CAP) {
        // ---- collect the L candidates sharing the 10-bit prefix ----
        unsigned* cd = h;                       // alias (first TK_CAP words)
        #pragma unroll
        for (int v = 0; v < 16; ++v) {
            uint4 q = u4[v];
            if ((q.x >> 22) == prefix) { unsigned p = atomicAdd(&ccnt[wid], 1u); cd[p] = q.x; }
            if ((q.y >> 22) == prefix) { unsigned p = atomicAdd(&ccnt[wid], 1u); cd[p] = q.y; }
            if ((q.z >> 22) == prefix) { unsigned p = atomicAdd(&ccnt[wid], 1u); cd[p] = q.z; }
            if ((q.w >> 22) == prefix) { unsigned p = atomicAdd(&ccnt[wid], 1u); cd[p] = q.w; }
        }
        tk_fence();

        // ---- exact rank among L (~88 expected) candidates ----
        int fnd = 0; unsigned mT = 0, mg = 0, me = 0;
        for (unsigned j = lane; j < L; j += 64) {
            unsigned uj = cd[j], g = 0, eq = 0;
            for (unsigned i = 0; i < L; ++i) {
                unsigned ui = cd[i];            // all-lane broadcast read
                g  += (ui > uj)  ? 1u : 0u;
                eq += (ui == uj) ? 1u : 0u;
            }
            if (g < r && g + eq >= r) { fnd = 1; mT = uj; mg = g; me = eq; }
        }
        unsigned long long mm = __ballot(fnd);
        int s2 = __ffsll(mm) - 1;
        T          = (unsigned)__shfl((int)mT, s2, 64);
        unsigned g = (unsigned)__shfl((int)mg, s2, 64);
        unsigned e = (unsigned)__shfl((int)me, s2, 64);
        re = r - g; easy = (e == re);
    } else {
        // pathological overflow: bit-by-bit wave-ballot bisection on low 22 bits
        unsigned pfx = prefix, rr = r;
        for (int sh = 21; sh >= 0; --sh) {
            unsigned cp = (pfx << 1) | 1u;
            unsigned c = 0;
            #pragma unroll
            for (int v = 0; v < 16; ++v) {
                uint4 q = u4[v];
                c += ((q.x >> sh) == cp) ? 1u : 0u;
                c += ((q.y >> sh) == cp) ? 1u : 0u;
                c += ((q.z >> sh) == cp) ? 1u : 0u;
                c += ((q.w >> sh) == cp) ? 1u : 0u;
            }
            #pragma unroll
            for (int d = 1; d < 64; d <<= 1) c += (unsigned)__shfl_xor((int)c, d, 64);
            if (c >= rr) pfx = cp; else { rr -= c; pfx <<= 1; }
        }
        T = pfx;
        unsigned ce = 0;
        #pragma unroll
        for (int v = 0; v < 16; ++v) {
            uint4 q = u4[v];
            ce += (q.x == T) ? 1u : 0u;
            ce += (q.y == T) ? 1u : 0u;
            ce += (q.z == T) ? 1u : 0u;
            ce += (q.w == T) ? 1u : 0u;
        }
        #pragma unroll
        for (int d = 1; d < 64; d <<= 1) ce += (unsigned)__shfl_xor((int)ce, d, 64);
        re = rr; easy = (ce == rr);
    }

    // ---- mask + single global write (from registers) ----
    const unsigned* xr = (const unsigned*)(x + (size_t)row * TK_F);
    #pragma unroll
    for (int v = 0; v < 16; ++v) {
        uint4 q = u4[v];
        uint4 o4;
        #pragma unroll
        for (int c = 0; c < 4; ++c) {
            unsigned uu  = (&q.x)[c];
            unsigned val = 0u;
            if (uu > T) {
                val = tk_u2f(uu);
            } else if (uu == T) {
                if (easy) {
                    val = tk_u2f(uu);
                } else {
                    int idx = 4 * (lane + 64 * v) + c;
                    if (tk_count_eq_before(xr, idx, T) < re) val = tk_u2f(uu);
                }
            }
            (&o4.x)[c] = val;
        }
        ov[lane + 64 * v] = o4;
    }
}

extern "C" void kernel_launch(void* const* d_in, const int* in_sizes, int n_in,
                              void* d_out, int out_size, void* d_ws, size_t ws_size,
                              hipStream_t stream) {
    const float* x   = (const float*)d_in[0];
    const int*   kpp = (const int*)d_in[1];
    float*       o   = (float*)d_out;
    const int B = in_sizes[0] / TK_F;
    const int grid = (B + TK_WPB - 1) / TK_WPB;
    hipLaunchKernelGGL(tk_topk_mask, dim3(grid), dim3(TK_THREADS), 0, stream,
                       x, kpp, o, B);
}